// Round 21
// baseline (142.919 us; speedup 1.0000x reference)
//
#include <hip/hip_runtime.h>
#include <hip/hip_bf16.h>
#include <math.h>

#define Bdim 2
#define Sdim 2048
#define Ddim 1024
#define Hdim 16
#define DKdim 64
#define Mrows 4096

typedef __attribute__((ext_vector_type(8))) short bf16x8;
typedef __attribute__((ext_vector_type(4))) short short4v;
typedef __attribute__((ext_vector_type(4))) float f32x4;
typedef __attribute__((ext_vector_type(2))) unsigned int uint2v;

#define LOG2E_DIV8 0.18033688011112042f   /* 0.125 * log2(e) */
#define NLOG2TH_64 0.20762050593046016f   /* log2(10000)/64 */

__device__ __forceinline__ short f2bf(float f) {
  unsigned int x = __float_as_uint(f);
  x += 0x7fffu + ((x >> 16) & 1u);   // RNE
  return (short)(x >> 16);
}

__device__ __forceinline__ float fast_exp2(float x) {
#if __has_builtin(__builtin_amdgcn_exp2f)
  return __builtin_amdgcn_exp2f(x);
#else
  return exp2f(x);
#endif
}

// pack two f32 -> one u32 of 2 bf16 (RNE), single v_cvt_pk_bf16_f32
__device__ __forceinline__ unsigned int pack_bf2(float lo, float hi) {
  unsigned int r;
  asm("v_cvt_pk_bf16_f32 %0, %1, %2" : "=v"(r) : "v"(lo), "v"(hi));
  return r;
}

// async global->LDS, 16B/lane. LDS dest = wave-uniform base + lane*16 (linear!).
// Global source is PER-LANE -> swizzled layouts via pre-swizzled source addr (m173).
__device__ __forceinline__ void gl2lds16(const void* g, void* l) {
  __builtin_amdgcn_global_load_lds(
      (const __attribute__((address_space(1))) void*)g,
      (__attribute__((address_space(3))) void*)l, 16, 0, 0);
}

// ---------------- merged prep: fp32->bf16 for X/Wq/Wk/Wv/Wo + RoPE table ----------------
__global__ __launch_bounds__(256) void prep_kernel(
    const float* __restrict__ X,  const float* __restrict__ Wq,
    const float* __restrict__ Wk, const float* __restrict__ Wv,
    const float* __restrict__ Wo,
    short* __restrict__ Xb, short* __restrict__ Wqkv, short* __restrict__ Wob,
    float2* __restrict__ RT)
{
  const int bid = blockIdx.x;
  if (bid < 8192) {
    int u = bid * 256 + threadIdx.x;          // one 4-elem unit per thread
    const float* src; short* dst; int base;
    if (u < 1048576)      { src = X;  dst = Xb;              base = u; }
    else if (u < 1310720) { src = Wq; dst = Wqkv;            base = u - 1048576; }
    else if (u < 1572864) { src = Wk; dst = Wqkv + 1048576;  base = u - 1310720; }
    else if (u < 1835008) { src = Wv; dst = Wqkv + 2097152;  base = u - 1572864; }
    else                  { src = Wo; dst = Wob;             base = u - 1835008; }
    int i = base * 4;
    float4 v = *(const float4*)(src + i);
    short4v o;
    o.x = f2bf(v.x); o.y = f2bf(v.y); o.z = f2bf(v.z); o.w = f2bf(v.w);
    *(short4v*)(dst + i) = o;
  } else {
    int idx = (bid - 8192) * 256 + threadIdx.x;   // 65536 RT entries
    int s = idx >> 5, f = idx & 31;
    float inv = exp2f(-NLOG2TH_64 * (float)(2 * f));
    float ang = (float)s * inv;
    float sn, cs;
    sincosf(ang, &sn, &cs);
    RT[idx] = make_float2(sn, cs);
  }
}

// ---------------- GEMM: C = A(bf16 MxK) * Bw(bf16 NxK)^T ----------------
// BM=128, BN=64, BK=32 (m97 staging). 4 waves, each owns 32x64 (acc[2][4]).
// BN=64 doubles blocks/CU (6 resident for QKV, 2 for O-proj) -> more independent
// barrier domains per SIMD to hide the per-step vmcnt drain (round-20: grid 768
// = 3/CU lockstep, MfmaUtil 19%). MODE 1 epilogue: tile spans exactly one head
// column-block (h block-uniform); Q gets RoPE + softmax scale; V transposed.
template<int MODE>
__global__ __launch_bounds__(256) void gemm_bt(
    const short* __restrict__ A, const short* __restrict__ Bw,
    float* __restrict__ Cf,
    short* __restrict__ Qout, short* __restrict__ Kout, short* __restrict__ Vout,
    const float2* __restrict__ RT,
    int Ndim, int Kdim)
{
  // K-loop: lA 128x32 @0 (8KB), lB 64x32 @8192 (4KB). Epilogue st[128][72] (18432B).
  __shared__ __align__(16) short smem[9216];
  short (*st)[72] = (short(*)[72])smem;
  char* smemb = (char*)smem;

  const int tid  = threadIdx.x;
  const int lane = tid & 63;
  const int wid  = tid >> 6;
  const int tile_m = blockIdx.x * 128;
  const int tile_n = blockIdx.y * 64;
  const int lrow = lane & 15;
  const int kgrp = lane >> 4;

  // staging: A chunks c=i*256+tid (i<2): row=c>>2, sub=(c&3)*8 elems.
  //          B chunks c=tid: row=c>>2 (0..63), sub=(c&3)*8.
  const int rA = tid >> 2;
  const int scA = (tid & 3) * 8;
  const short* gA0 = A  + (size_t)(tile_m + rA)      * Kdim + scA;
  const short* gA1 = A  + (size_t)(tile_m + rA + 64) * Kdim + scA;
  const short* gB0 = Bw + (size_t)(tile_n + (tid >> 2)) * Kdim + scA;
  const int ldsA0 = wid * 1024;
  const int ldsA1 = 4096 + wid * 1024;
  const int ldsB  = 8192 + wid * 1024;

  f32x4 acc[2][4];
#pragma unroll
  for (int i = 0; i < 2; i++)
#pragma unroll
    for (int j = 0; j < 4; j++) acc[i][j] = (f32x4)0.0f;

  for (int k0 = 0; k0 < Kdim; k0 += 32) {
    __syncthreads();                 // prev compute done reading LDS
    gl2lds16(gA0 + k0, smemb + ldsA0);
    gl2lds16(gA1 + k0, smemb + ldsA1);
    gl2lds16(gB0 + k0, smemb + ldsB);
    __syncthreads();                 // vmcnt(0) drain -> data landed
    bf16x8 af[2], bfr[4];
#pragma unroll
    for (int i = 0; i < 2; i++)
      af[i]  = *(const bf16x8*)&smem[(wid*32 + i*16 + lrow)*32 + kgrp*8];
#pragma unroll
    for (int j = 0; j < 4; j++)
      bfr[j] = *(const bf16x8*)&smem[4096 + (j*16 + lrow)*32 + kgrp*8];
#pragma unroll
    for (int i = 0; i < 2; i++)
#pragma unroll
      for (int j = 0; j < 4; j++)
        acc[i][j] = __builtin_amdgcn_mfma_f32_16x16x32_bf16(af[i], bfr[j], acc[i][j], 0, 0, 0);
  }

  if (MODE == 0) {
#pragma unroll
    for (int i = 0; i < 2; i++)
#pragma unroll
      for (int j = 0; j < 4; j++)
#pragma unroll
        for (int r = 0; r < 4; r++) {
          int mr = tile_m + wid*32 + i*16 + kgrp*4 + r;
          int nc = tile_n + j*16 + lrow;
          Cf[(size_t)mr * Ndim + nc] = acc[i][j][r];
        }
  } else {
    const int sel = tile_n >> 10;           // block-uniform (64 | 1024)
    const int h   = (tile_n & 1023) >> 6;   // block-uniform head
    __syncthreads();                        // all waves done with lA/lB
    // ---- stage rope'd bf16 tile (128 x 64) into st[128][72] ----
#pragma unroll
    for (int i = 0; i < 2; i++)
#pragma unroll
      for (int j = 0; j < 4; j++)
#pragma unroll
        for (int r = 0; r < 4; r++) {
          float val   = acc[i][j][r];
          float other = __shfl_xor(val, 1, 64);   // adjacent column, same row
          int row = wid*32 + i*16 + kgrp*4 + r;
          int col = j*16 + lrow;                  // 0..63 == c within head
          short bv;
          if (sel == 2) {
            bv = f2bf(val);
          } else {
            int s = (tile_m + row) & 2047;
            float2 t = RT[(s << 5) + (col >> 1)];
            float rot = ((col & 1) == 0) ? (val * t.y - other * t.x)
                                         : (other * t.x + val * t.y);
            if (sel == 0) rot *= LOG2E_DIV8;
            bv = f2bf(rot);
          }
          st[row][col] = bv;
        }
    __syncthreads();
    // ---- wide coalesced stores from LDS ----
    if (sel < 2) {
      short* Out = (sel == 0) ? Qout : Kout;
#pragma unroll
      for (int p = 0; p < 4; p++) {
        int row = p*32 + (tid >> 3);
        int col = (tid & 7) * 8;
        bf16x8 v = *(const bf16x8*)&st[row][col];
        int mr = tile_m + row; int b = mr >> 11, s = mr & 2047;
        *(bf16x8*)&Out[((size_t)((b*Hdim + h)*Sdim + s))*DKdim + col] = v;
      }
    } else {
#pragma unroll
      for (int p = 0; p < 4; p++) {
        int c  = p*16 + (tid >> 4);        // 0..63 column within head
        int sl = (tid & 15) * 8;           // row block of 8
        bf16x8 v;
#pragma unroll
        for (int e = 0; e < 8; e++) v[e] = st[sl + e][c];
        int m0 = tile_m + sl; int b = m0 >> 11, s0 = m0 & 2047;
        *(bf16x8*)&Vout[((size_t)((b*Hdim + h)*DKdim + c))*Sdim + s0] = v;
      }
    }
  }
}

// ---------------- flash attention, causal — KVBLK=128, gload_lds staging ----------------
// (round-17/20, passing) 1 block = 128 q-rows, 4 waves x 32 rows.
// K [128][128B] + V [64][256B] double-buffered; staging via global_load_lds
// with linear dest + pre-swizzled source; swapped QK^T P-path.
__global__ __launch_bounds__(256, 2) void attn_kernel(
    const short* __restrict__ Q, const short* __restrict__ K,
    const short* __restrict__ Vt, short* __restrict__ O)
{
  const int bh = blockIdx.y;
  const int qt = (bh & 16) ? (int)blockIdx.x : (15 - (int)blockIdx.x);
  const int bq0 = qt * 128;
  const int tid  = threadIdx.x;
  const int wave = tid >> 6;
  const int lane = tid & 63;
  const int lrow = lane & 15, kgrp = lane >> 4;
  const short* Qb = Q  + (size_t)bh * Sdim * DKdim;
  const short* Kb = K  + (size_t)bh * Sdim * DKdim;
  const short* Vb = Vt + (size_t)bh * DKdim * Sdim;

  __shared__ __align__(16) char Kl[2][16384];  // [buf][128 kv rows][128 B]
  __shared__ __align__(16) char Vl[2][16384];  // [buf][64 d rows][256 B]
  __shared__ __align__(16) char lPb[16384];    // per-wave P scratch (4KB each)

  const int q0w   = bq0 + wave*32;
  const int NT_w  = (q0w >> 6) + 1;            // this wave's causal 64-tile count
  const int NTP   = qt + 1;                    // block 128-tile count
  const int swz   = (lrow & 7) << 4;
  const int rowbase = wave*4096 + lrow*128;

  const int ldsoff = wave*4096;

  // Q fragments (B-operand), pre-scaled
  bf16x8 qf[2][2];
#pragma unroll
  for (int t = 0; t < 2; t++) {
    qf[t][0] = *(const bf16x8*)&Qb[(q0w + t*16 + lrow) * DKdim + kgrp*8];
    qf[t][1] = *(const bf16x8*)&Qb[(q0w + t*16 + lrow) * DKdim + 32 + kgrp*8];
  }

  f32x4 o[2][4];
  float psum[2] = {0.0f, 0.0f};
#pragma unroll
  for (int t = 0; t < 2; t++)
#pragma unroll
    for (int n = 0; n < 4; n++) o[t][n] = (f32x4)0.0f;

  // ---- prologue: stage 128-tile 0 via global_load_lds ----
#pragma unroll
  for (int q = 0; q < 4; q++) {
    int c = wave*256 + q*64 + lane;
    int krow = c >> 3, kc16 = c & 7;
    gl2lds16((const char*)Kb + (size_t)krow * 128 + ((kc16*16) ^ ((krow & 7) << 4)),
             (char*)Kl[0] + ldsoff + q*1024);
    int vrow = c >> 4, vc16 = c & 15;
    gl2lds16((const char*)Vb + (size_t)vrow * (Sdim*2) + ((vc16*16) ^ ((vrow & 7) << 4)),
             (char*)Vl[0] + ldsoff + q*1024);
  }
  __syncthreads();

  int cur = 0;
  for (int it = 0; it < NTP; ++it) {
    const bool havenext = (it + 1 < NTP);
    // ---- issue next 128-tile gload_lds into the other buffer (async) ----
    if (havenext) {
      const int nkv = (it + 1) << 7;
      char* Kd = (char*)Kl[cur ^ 1] + ldsoff;
      char* Vd = (char*)Vl[cur ^ 1] + ldsoff;
#pragma unroll
      for (int q = 0; q < 4; q++) {
        int c = wave*256 + q*64 + lane;
        int krow = c >> 3, kc16 = c & 7;
        gl2lds16((const char*)Kb + (size_t)(nkv + krow) * 128 + ((kc16*16) ^ ((krow & 7) << 4)),
                 Kd + q*1024);
        int vrow = c >> 4, vc16 = c & 15;
        gl2lds16((const char*)Vb + (size_t)vrow * (Sdim*2) + nkv*2 + ((vc16*16) ^ ((vrow & 7) << 4)),
                 Vd + q*1024);
      }
    }
    // ---- two 64-wide sub-tiles over the staged 128-tile ----
#pragma unroll
    for (int stt = 0; stt < 2; ++stt) {
      const int j = 2*it + stt;            // global 64-tile index
      if (j < NT_w) {
        const int kv0 = j << 6;
        const char* Kc = Kl[cur] + stt*8192;
        const char* Vc = Vl[cur];
        const int vbo = stt*128;
        f32x4 sacc[2][4];
#pragma unroll
        for (int t = 0; t < 2; t++)
#pragma unroll
          for (int nch = 0; nch < 4; nch++) sacc[t][nch] = (f32x4)0.0f;
        __builtin_amdgcn_s_setprio(1);
#pragma unroll
        for (int nch = 0; nch < 4; nch++) {
          int rb = (nch*16 + lrow)*128;
          bf16x8 kf0 = *(const bf16x8*)(Kc + rb + ((kgrp*16) ^ swz));
          bf16x8 kf1 = *(const bf16x8*)(Kc + rb + ((kgrp*16 + 64) ^ swz));
          sacc[0][nch] = __builtin_amdgcn_mfma_f32_16x16x32_bf16(kf0, qf[0][0], sacc[0][nch], 0, 0, 0);
          sacc[0][nch] = __builtin_amdgcn_mfma_f32_16x16x32_bf16(kf1, qf[0][1], sacc[0][nch], 0, 0, 0);
          sacc[1][nch] = __builtin_amdgcn_mfma_f32_16x16x32_bf16(kf0, qf[1][0], sacc[1][nch], 0, 0, 0);
          sacc[1][nch] = __builtin_amdgcn_mfma_f32_16x16x32_bf16(kf1, qf[1][1], sacc[1][nch], 0, 0, 0);
        }
        __builtin_amdgcn_s_setprio(0);
        const bool diag = (j == NT_w - 1);
#pragma unroll
        for (int t = 0; t < 2; t++) {
          const int q_abs = q0w + t*16 + lrow;
#pragma unroll
          for (int nch = 0; nch < 4; nch++) {
            const int kbase = kv0 + nch*16 + kgrp*4;
            float p[4];
#pragma unroll
            for (int r = 0; r < 4; r++) {
              float e = fast_exp2(sacc[t][nch][r]);
              p[r] = (diag && (kbase + r > q_abs)) ? 0.0f : e;
            }
            psum[t] += (p[0] + p[1]) + (p[2] + p[3]);
            uint2v w;
            w.x = pack_bf2(p[0], p[1]);
            w.y = pack_bf2(p[2], p[3]);
            *(uint2v*)(lPb + rowbase + t*2048 + ((nch*32 + kgrp*8) ^ swz)) = w;
          }
        }
        asm volatile("s_waitcnt lgkmcnt(0)" ::: "memory");
        __builtin_amdgcn_sched_barrier(0);
        bf16x8 pa[2][2];
#pragma unroll
        for (int t = 0; t < 2; t++)
#pragma unroll
          for (int h = 0; h < 2; h++)
            pa[t][h] = *(const bf16x8*)(lPb + rowbase + t*2048 + ((h*64 + kgrp*16) ^ swz));
        __builtin_amdgcn_s_setprio(1);
#pragma unroll
        for (int n = 0; n < 4; n++) {
          int rb = (n*16 + lrow)*256 + vbo;
          bf16x8 vf0 = *(const bf16x8*)(Vc + rb + ((kgrp*16) ^ swz));
          bf16x8 vf1 = *(const bf16x8*)(Vc + rb + ((kgrp*16 + 64) ^ swz));
          o[0][n] = __builtin_amdgcn_mfma_f32_16x16x32_bf16(pa[0][0], vf0, o[0][n], 0, 0, 0);
          o[0][n] = __builtin_amdgcn_mfma_f32_16x16x32_bf16(pa[0][1], vf1, o[0][n], 0, 0, 0);
          o[1][n] = __builtin_amdgcn_mfma_f32_16x16x32_bf16(pa[1][0], vf0, o[1][n], 0, 0, 0);
          o[1][n] = __builtin_amdgcn_mfma_f32_16x16x32_bf16(pa[1][1], vf1, o[1][n], 0, 0, 0);
        }
        __builtin_amdgcn_s_setprio(0);
      }
    }
    // barrier: drains vmcnt(0) -> next buffer staged; also fences buffer swap
    __syncthreads();
    cur ^= 1;
  }

  // ---- epilogue: row-sums wave-local; redistribute via shuffles ----
  float vt[2];
#pragma unroll
  for (int t = 0; t < 2; t++) {
    float v = psum[t];
    v += __shfl_xor(v, 16, 64);
    v += __shfl_xor(v, 32, 64);
    vt[t] = v;
  }
  const int hh = bh & 15, b = bh >> 4;
#pragma unroll
  for (int t = 0; t < 2; t++)
#pragma unroll
    for (int r = 0; r < 4; r++) {
      float rs = __frcp_rn(__shfl(vt[t], kgrp*4 + r, 64));
      int row = q0w + t*16 + kgrp*4 + r;
#pragma unroll
      for (int n = 0; n < 4; n++) {
        int col = hh*64 + n*16 + lrow;
        O[(size_t)(b*Sdim + row) * Ddim + col] = f2bf(o[t][n][r] * rs);
      }
    }
}

// ---------------- launch ----------------
extern "C" void kernel_launch(void* const* d_in, const int* in_sizes, int n_in,
                              void* d_out, int out_size, void* d_ws, size_t ws_size,
                              hipStream_t stream) {
  const float* X  = (const float*)d_in[0];
  const float* Wq = (const float*)d_in[1];
  const float* Wk = (const float*)d_in[2];
  const float* Wv = (const float*)d_in[3];
  const float* Wo = (const float*)d_in[4];
  float* out = (float*)d_out;
  char* ws = (char*)d_ws;

  short* Xb   = (short*)(ws);                    //  8 MB  [4096][1024]
  short* Wqkv = (short*)(ws + 8388608);          //  6 MB  [3072][1024]
  short* Wob  = (short*)(ws + 14680064);         //  2 MB  [1024][1024]
  short* Qr   = (short*)(ws + 16777216);         //  8 MB  [BH][S][64]
  short* Kr   = (short*)(ws + 25165824);         //  8 MB  [BH][S][64]
  short* Vt   = (short*)(ws + 33554432);         //  8 MB  [BH][64][S]
  short* Ob   = (short*)(ws + 41943040);         //  8 MB  [4096][1024]
  float2* RT  = (float2*)(ws + 41943040);        // 512 KB, aliases Ob (consumed first)

  prep_kernel<<<8448, 256, 0, stream>>>(X, Wq, Wk, Wv, Wo, Xb, Wqkv, Wob, RT);

  gemm_bt<1><<<dim3(32, 48), 256, 0, stream>>>(Xb, Wqkv, (float*)nullptr,
                                               Qr, Kr, Vt, RT, 3072, 1024);
  attn_kernel<<<dim3(16, 32), 256, 0, stream>>>(Qr, Kr, Vt, Ob);
  gemm_bt<0><<<dim3(32, 16), 256, 0, stream>>>(Ob, Wob, out,
                                               nullptr, nullptr, nullptr, RT, 1024, 1024);
}

// Round 22
// 133.535 us; speedup vs baseline: 1.0703x; 1.0703x over previous
//
#include <hip/hip_runtime.h>
#include <hip/hip_bf16.h>
#include <math.h>

#define Bdim 2
#define Sdim 2048
#define Ddim 1024
#define Hdim 16
#define DKdim 64
#define Mrows 4096

typedef __attribute__((ext_vector_type(8))) short bf16x8;
typedef __attribute__((ext_vector_type(4))) short short4v;
typedef __attribute__((ext_vector_type(4))) float f32x4;
typedef __attribute__((ext_vector_type(2))) unsigned int uint2v;

#define LOG2E_DIV8 0.18033688011112042f   /* 0.125 * log2(e) */
#define NLOG2TH_64 0.20762050593046016f   /* log2(10000)/64 */

__device__ __forceinline__ short f2bf(float f) {
  unsigned int x = __float_as_uint(f);
  x += 0x7fffu + ((x >> 16) & 1u);   // RNE
  return (short)(x >> 16);
}

__device__ __forceinline__ float fast_exp2(float x) {
#if __has_builtin(__builtin_amdgcn_exp2f)
  return __builtin_amdgcn_exp2f(x);
#else
  return exp2f(x);
#endif
}

// pack two f32 -> one u32 of 2 bf16 (RNE), single v_cvt_pk_bf16_f32
__device__ __forceinline__ unsigned int pack_bf2(float lo, float hi) {
  unsigned int r;
  asm("v_cvt_pk_bf16_f32 %0, %1, %2" : "=v"(r) : "v"(lo), "v"(hi));
  return r;
}

// async global->LDS, 16B/lane. LDS dest = wave-uniform base + lane*16 (linear!).
// Global source is PER-LANE -> swizzled layouts via pre-swizzled source addr (m173).
__device__ __forceinline__ void gl2lds16(const void* g, void* l) {
  __builtin_amdgcn_global_load_lds(
      (const __attribute__((address_space(1))) void*)g,
      (__attribute__((address_space(3))) void*)l, 16, 0, 0);
}

// ---------------- merged prep: fp32->bf16 for X/Wq/Wk/Wv/Wo + RoPE table ----------------
// Region boundaries are multiples of 256 units -> block-uniform branches.
__global__ __launch_bounds__(256) void prep_kernel(
    const float* __restrict__ X,  const float* __restrict__ Wq,
    const float* __restrict__ Wk, const float* __restrict__ Wv,
    const float* __restrict__ Wo,
    short* __restrict__ Xb, short* __restrict__ Wqkv, short* __restrict__ Wob,
    float2* __restrict__ RT)
{
  const int bid = blockIdx.x;
  if (bid < 8192) {
    int u = bid * 256 + threadIdx.x;          // one 4-elem unit per thread
    const float* src; short* dst; int base;
    if (u < 1048576)      { src = X;  dst = Xb;              base = u; }
    else if (u < 1310720) { src = Wq; dst = Wqkv;            base = u - 1048576; }
    else if (u < 1572864) { src = Wk; dst = Wqkv + 1048576;  base = u - 1310720; }
    else if (u < 1835008) { src = Wv; dst = Wqkv + 2097152;  base = u - 1572864; }
    else                  { src = Wo; dst = Wob;             base = u - 1835008; }
    int i = base * 4;
    float4 v = *(const float4*)(src + i);
    short4v o;
    o.x = f2bf(v.x); o.y = f2bf(v.y); o.z = f2bf(v.z); o.w = f2bf(v.w);
    *(short4v*)(dst + i) = o;
  } else {
    int idx = (bid - 8192) * 256 + threadIdx.x;   // 65536 RT entries
    int s = idx >> 5, f = idx & 31;
    float inv = exp2f(-NLOG2TH_64 * (float)(2 * f));
    float ang = (float)s * inv;
    float sn, cs;
    sincosf(ang, &sn, &cs);
    RT[idx] = make_float2(sn, cs);
  }
}

// ---------------- GEMM: C = A(bf16 MxK) * Bw(bf16 NxK)^T ----------------
// K-loop staging via global_load_lds width=16 (m97 pattern, BK=32 — proven 53us;
// BK=64-swizzle, XCD-swizzle and BN=64 variants all regressed).
// MODE 1 epilogue: Q gets RoPE + softmax scale; V transposed store.
template<int MODE>
__global__ __launch_bounds__(256) void gemm_bt(
    const short* __restrict__ A, const short* __restrict__ Bw,
    float* __restrict__ Cf,
    short* __restrict__ Qout, short* __restrict__ Kout, short* __restrict__ Vout,
    const float2* __restrict__ RT,
    int Ndim, int Kdim)
{
  __shared__ __align__(16) short smem[17408];
  short (*st)[136] = (short(*)[136])smem;
  char* smemb = (char*)smem;

  const int tid  = threadIdx.x;
  const int lane = tid & 63;
  const int wid  = tid >> 6;
  const int wr = wid >> 1, wc = wid & 1;
  const int tile_m = blockIdx.x * 128;
  const int tile_n = blockIdx.y * 128;
  const int lrow = lane & 15;
  const int kgrp = lane >> 4;

  const int r0 = tid >> 2;
  const int sc = (tid & 3) * 8;
  const int lA0 = wid * 1024;
  const int lA1 = 4096  + wid * 1024;
  const int lB0 = 8192  + wid * 1024;
  const int lB1 = 12288 + wid * 1024;
  const short* gA0 = A  + (size_t)(tile_m + r0)      * Kdim + sc;
  const short* gA1 = A  + (size_t)(tile_m + r0 + 64) * Kdim + sc;
  const short* gB0 = Bw + (size_t)(tile_n + r0)      * Kdim + sc;
  const short* gB1 = Bw + (size_t)(tile_n + r0 + 64) * Kdim + sc;

  f32x4 acc[4][4];
#pragma unroll
  for (int i = 0; i < 4; i++)
#pragma unroll
    for (int j = 0; j < 4; j++) acc[i][j] = (f32x4)0.0f;

  for (int k0 = 0; k0 < Kdim; k0 += 32) {
    __syncthreads();
    gl2lds16(gA0 + k0, smemb + lA0);
    gl2lds16(gA1 + k0, smemb + lA1);
    gl2lds16(gB0 + k0, smemb + lB0);
    gl2lds16(gB1 + k0, smemb + lB1);
    __syncthreads();
    bf16x8 af[4], bfr[4];
#pragma unroll
    for (int i = 0; i < 4; i++)
      af[i]  = *(const bf16x8*)&smem[(wr*64 + i*16 + lrow)*32 + kgrp*8];
#pragma unroll
    for (int j = 0; j < 4; j++)
      bfr[j] = *(const bf16x8*)&smem[4096 + (wc*64 + j*16 + lrow)*32 + kgrp*8];
#pragma unroll
    for (int i = 0; i < 4; i++)
#pragma unroll
      for (int j = 0; j < 4; j++)
        acc[i][j] = __builtin_amdgcn_mfma_f32_16x16x32_bf16(af[i], bfr[j], acc[i][j], 0, 0, 0);
  }

  if (MODE == 0) {
#pragma unroll
    for (int i = 0; i < 4; i++)
#pragma unroll
      for (int j = 0; j < 4; j++)
#pragma unroll
        for (int r = 0; r < 4; r++) {
          int mr = tile_m + wr*64 + i*16 + kgrp*4 + r;
          int nc = tile_n + wc*64 + j*16 + lrow;
          Cf[(size_t)mr * Ndim + nc] = acc[i][j][r];
        }
  } else {
    const int sel = tile_n >> 10;
    __syncthreads();
#pragma unroll
    for (int i = 0; i < 4; i++)
#pragma unroll
      for (int j = 0; j < 4; j++)
#pragma unroll
        for (int r = 0; r < 4; r++) {
          float val   = acc[i][j][r];
          float other = __shfl_xor(val, 1, 64);
          int row = wr*64 + i*16 + kgrp*4 + r;
          int col = wc*64 + j*16 + lrow;
          short bv;
          if (sel == 2) {
            bv = f2bf(val);
          } else {
            int c = col & 63;
            int s = (tile_m + row) & 2047;
            float2 t = RT[(s << 5) + (c >> 1)];
            float rot = ((c & 1) == 0) ? (val * t.y - other * t.x)
                                       : (other * t.x + val * t.y);
            if (sel == 0) rot *= LOG2E_DIV8;
            bv = f2bf(rot);
          }
          st[row][col] = bv;
        }
    __syncthreads();
    if (sel < 2) {
      short* Out = (sel == 0) ? Qout : Kout;
#pragma unroll
      for (int p = 0; p < 8; p++) {
        int row = p*16 + (tid >> 4);
        int col = (tid & 15) * 8;
        bf16x8 v = *(const bf16x8*)&st[row][col];
        int mr = tile_m + row; int b = mr >> 11, s = mr & 2047;
        int nc = tile_n + col; int nn = nc & 1023;
        int h = nn >> 6, c = nn & 63;
        *(bf16x8*)&Out[((size_t)((b*Hdim + h)*Sdim + s))*DKdim + c] = v;
      }
    } else {
#pragma unroll
      for (int p = 0; p < 8; p++) {
        int col = p*16 + (tid >> 4);
        int sl  = (tid & 15) * 8;
        bf16x8 v;
#pragma unroll
        for (int e = 0; e < 8; e++) v[e] = st[sl + e][col];
        int nc = tile_n + col; int nn = nc & 1023;
        int h = nn >> 6, c = nn & 63;
        int m0 = tile_m + sl; int b = m0 >> 11, s0 = m0 & 2047;
        *(bf16x8*)&Vout[((size_t)((b*Hdim + h)*DKdim + c))*Sdim + s0] = v;
      }
    }
  }
}

// ---------------- flash attention, causal — KVBLK=128, gload_lds staging ----------------
// (round-17/20, passing) 1 block = 128 q-rows, 4 waves x 32 rows.
// K [128][128B] + V [64][256B] double-buffered; staging via global_load_lds
// with linear dest + pre-swizzled source; swapped QK^T P-path.
__global__ __launch_bounds__(256, 2) void attn_kernel(
    const short* __restrict__ Q, const short* __restrict__ K,
    const short* __restrict__ Vt, short* __restrict__ O)
{
  const int bh = blockIdx.y;
  const int qt = (bh & 16) ? (int)blockIdx.x : (15 - (int)blockIdx.x);
  const int bq0 = qt * 128;
  const int tid  = threadIdx.x;
  const int wave = tid >> 6;
  const int lane = tid & 63;
  const int lrow = lane & 15, kgrp = lane >> 4;
  const short* Qb = Q  + (size_t)bh * Sdim * DKdim;
  const short* Kb = K  + (size_t)bh * Sdim * DKdim;
  const short* Vb = Vt + (size_t)bh * DKdim * Sdim;

  __shared__ __align__(16) char Kl[2][16384];  // [buf][128 kv rows][128 B]
  __shared__ __align__(16) char Vl[2][16384];  // [buf][64 d rows][256 B]
  __shared__ __align__(16) char lPb[16384];    // per-wave P scratch (4KB each)

  const int q0w   = bq0 + wave*32;
  const int NT_w  = (q0w >> 6) + 1;            // this wave's causal 64-tile count
  const int NTP   = qt + 1;                    // block 128-tile count
  const int swz   = (lrow & 7) << 4;
  const int rowbase = wave*4096 + lrow*128;

  const int ldsoff = wave*4096;

  // Q fragments (B-operand), pre-scaled
  bf16x8 qf[2][2];
#pragma unroll
  for (int t = 0; t < 2; t++) {
    qf[t][0] = *(const bf16x8*)&Qb[(q0w + t*16 + lrow) * DKdim + kgrp*8];
    qf[t][1] = *(const bf16x8*)&Qb[(q0w + t*16 + lrow) * DKdim + 32 + kgrp*8];
  }

  f32x4 o[2][4];
  float psum[2] = {0.0f, 0.0f};
#pragma unroll
  for (int t = 0; t < 2; t++)
#pragma unroll
    for (int n = 0; n < 4; n++) o[t][n] = (f32x4)0.0f;

  // ---- prologue: stage 128-tile 0 via global_load_lds ----
#pragma unroll
  for (int q = 0; q < 4; q++) {
    int c = wave*256 + q*64 + lane;
    int krow = c >> 3, kc16 = c & 7;
    gl2lds16((const char*)Kb + (size_t)krow * 128 + ((kc16*16) ^ ((krow & 7) << 4)),
             (char*)Kl[0] + ldsoff + q*1024);
    int vrow = c >> 4, vc16 = c & 15;
    gl2lds16((const char*)Vb + (size_t)vrow * (Sdim*2) + ((vc16*16) ^ ((vrow & 7) << 4)),
             (char*)Vl[0] + ldsoff + q*1024);
  }
  __syncthreads();

  int cur = 0;
  for (int it = 0; it < NTP; ++it) {
    const bool havenext = (it + 1 < NTP);
    // ---- issue next 128-tile gload_lds into the other buffer (async) ----
    if (havenext) {
      const int nkv = (it + 1) << 7;
      char* Kd = (char*)Kl[cur ^ 1] + ldsoff;
      char* Vd = (char*)Vl[cur ^ 1] + ldsoff;
#pragma unroll
      for (int q = 0; q < 4; q++) {
        int c = wave*256 + q*64 + lane;
        int krow = c >> 3, kc16 = c & 7;
        gl2lds16((const char*)Kb + (size_t)(nkv + krow) * 128 + ((kc16*16) ^ ((krow & 7) << 4)),
                 Kd + q*1024);
        int vrow = c >> 4, vc16 = c & 15;
        gl2lds16((const char*)Vb + (size_t)vrow * (Sdim*2) + nkv*2 + ((vc16*16) ^ ((vrow & 7) << 4)),
                 Vd + q*1024);
      }
    }
    // ---- two 64-wide sub-tiles over the staged 128-tile ----
#pragma unroll
    for (int stt = 0; stt < 2; ++stt) {
      const int j = 2*it + stt;            // global 64-tile index
      if (j < NT_w) {
        const int kv0 = j << 6;
        const char* Kc = Kl[cur] + stt*8192;
        const char* Vc = Vl[cur];
        const int vbo = stt*128;
        f32x4 sacc[2][4];
#pragma unroll
        for (int t = 0; t < 2; t++)
#pragma unroll
          for (int nch = 0; nch < 4; nch++) sacc[t][nch] = (f32x4)0.0f;
        __builtin_amdgcn_s_setprio(1);
#pragma unroll
        for (int nch = 0; nch < 4; nch++) {
          int rb = (nch*16 + lrow)*128;
          bf16x8 kf0 = *(const bf16x8*)(Kc + rb + ((kgrp*16) ^ swz));
          bf16x8 kf1 = *(const bf16x8*)(Kc + rb + ((kgrp*16 + 64) ^ swz));
          sacc[0][nch] = __builtin_amdgcn_mfma_f32_16x16x32_bf16(kf0, qf[0][0], sacc[0][nch], 0, 0, 0);
          sacc[0][nch] = __builtin_amdgcn_mfma_f32_16x16x32_bf16(kf1, qf[0][1], sacc[0][nch], 0, 0, 0);
          sacc[1][nch] = __builtin_amdgcn_mfma_f32_16x16x32_bf16(kf0, qf[1][0], sacc[1][nch], 0, 0, 0);
          sacc[1][nch] = __builtin_amdgcn_mfma_f32_16x16x32_bf16(kf1, qf[1][1], sacc[1][nch], 0, 0, 0);
        }
        __builtin_amdgcn_s_setprio(0);
        const bool diag = (j == NT_w - 1);
#pragma unroll
        for (int t = 0; t < 2; t++) {
          const int q_abs = q0w + t*16 + lrow;
#pragma unroll
          for (int nch = 0; nch < 4; nch++) {
            const int kbase = kv0 + nch*16 + kgrp*4;
            float p[4];
#pragma unroll
            for (int r = 0; r < 4; r++) {
              float e = fast_exp2(sacc[t][nch][r]);
              p[r] = (diag && (kbase + r > q_abs)) ? 0.0f : e;
            }
            psum[t] += (p[0] + p[1]) + (p[2] + p[3]);
            uint2v w;
            w.x = pack_bf2(p[0], p[1]);
            w.y = pack_bf2(p[2], p[3]);
            *(uint2v*)(lPb + rowbase + t*2048 + ((nch*32 + kgrp*8) ^ swz)) = w;
          }
        }
        asm volatile("s_waitcnt lgkmcnt(0)" ::: "memory");
        __builtin_amdgcn_sched_barrier(0);
        bf16x8 pa[2][2];
#pragma unroll
        for (int t = 0; t < 2; t++)
#pragma unroll
          for (int h = 0; h < 2; h++)
            pa[t][h] = *(const bf16x8*)(lPb + rowbase + t*2048 + ((h*64 + kgrp*16) ^ swz));
        __builtin_amdgcn_s_setprio(1);
#pragma unroll
        for (int n = 0; n < 4; n++) {
          int rb = (n*16 + lrow)*256 + vbo;
          bf16x8 vf0 = *(const bf16x8*)(Vc + rb + ((kgrp*16) ^ swz));
          bf16x8 vf1 = *(const bf16x8*)(Vc + rb + ((kgrp*16 + 64) ^ swz));
          o[0][n] = __builtin_amdgcn_mfma_f32_16x16x32_bf16(pa[0][0], vf0, o[0][n], 0, 0, 0);
          o[0][n] = __builtin_amdgcn_mfma_f32_16x16x32_bf16(pa[0][1], vf1, o[0][n], 0, 0, 0);
          o[1][n] = __builtin_amdgcn_mfma_f32_16x16x32_bf16(pa[1][0], vf0, o[1][n], 0, 0, 0);
          o[1][n] = __builtin_amdgcn_mfma_f32_16x16x32_bf16(pa[1][1], vf1, o[1][n], 0, 0, 0);
        }
        __builtin_amdgcn_s_setprio(0);
      }
    }
    // barrier: drains vmcnt(0) -> next buffer staged; also fences buffer swap
    __syncthreads();
    cur ^= 1;
  }

  // ---- epilogue: row-sums wave-local; redistribute via shuffles ----
  float vt[2];
#pragma unroll
  for (int t = 0; t < 2; t++) {
    float v = psum[t];
    v += __shfl_xor(v, 16, 64);
    v += __shfl_xor(v, 32, 64);
    vt[t] = v;
  }
  const int hh = bh & 15, b = bh >> 4;
#pragma unroll
  for (int t = 0; t < 2; t++)
#pragma unroll
    for (int r = 0; r < 4; r++) {
      float rs = __frcp_rn(__shfl(vt[t], kgrp*4 + r, 64));
      int row = q0w + t*16 + kgrp*4 + r;
#pragma unroll
      for (int n = 0; n < 4; n++) {
        int col = hh*64 + n*16 + lrow;
        O[(size_t)(b*Sdim + row) * Ddim + col] = f2bf(o[t][n][r] * rs);
      }
    }
}

// ---------------- launch ----------------
extern "C" void kernel_launch(void* const* d_in, const int* in_sizes, int n_in,
                              void* d_out, int out_size, void* d_ws, size_t ws_size,
                              hipStream_t stream) {
  const float* X  = (const float*)d_in[0];
  const float* Wq = (const float*)d_in[1];
  const float* Wk = (const float*)d_in[2];
  const float* Wv = (const float*)d_in[3];
  const float* Wo = (const float*)d_in[4];
  float* out = (float*)d_out;
  char* ws = (char*)d_ws;

  short* Xb   = (short*)(ws);                    //  8 MB  [4096][1024]
  short* Wqkv = (short*)(ws + 8388608);          //  6 MB  [3072][1024]
  short* Wob  = (short*)(ws + 14680064);         //  2 MB  [1024][1024]
  short* Qr   = (short*)(ws + 16777216);         //  8 MB  [BH][S][64]
  short* Kr   = (short*)(ws + 25165824);         //  8 MB  [BH][S][64]
  short* Vt   = (short*)(ws + 33554432);         //  8 MB  [BH][64][S]
  short* Ob   = (short*)(ws + 41943040);         //  8 MB  [4096][1024]
  float2* RT  = (float2*)(ws + 41943040);        // 512 KB, aliases Ob (consumed first)

  prep_kernel<<<8448, 256, 0, stream>>>(X, Wq, Wk, Wv, Wo, Xb, Wqkv, Wob, RT);

  gemm_bt<1><<<dim3(32, 24), 256, 0, stream>>>(Xb, Wqkv, (float*)nullptr,
                                               Qr, Kr, Vt, RT, 3072, 1024);
  attn_kernel<<<dim3(16, 32), 256, 0, stream>>>(Qr, Kr, Vt, Ob);
  gemm_bt<0><<<dim3(32, 8), 256, 0, stream>>>(Ob, Wob, out,
                                              nullptr, nullptr, nullptr, RT, 1024, 1024);
}

// Round 23
// 122.965 us; speedup vs baseline: 1.1623x; 1.0860x over previous
//
#include <hip/hip_runtime.h>
#include <hip/hip_bf16.h>
#include <math.h>

#define Bdim 2
#define Sdim 2048
#define Ddim 1024
#define Hdim 16
#define DKdim 64
#define Mrows 4096

typedef __attribute__((ext_vector_type(8))) short bf16x8;
typedef __attribute__((ext_vector_type(4))) short short4v;
typedef __attribute__((ext_vector_type(4))) float f32x4;
typedef __attribute__((ext_vector_type(2))) unsigned int uint2v;

#define LOG2E_DIV8 0.18033688011112042f   /* 0.125 * log2(e) */
#define NLOG2TH_64 0.20762050593046016f   /* log2(10000)/64 */

__device__ __forceinline__ short f2bf(float f) {
  unsigned int x = __float_as_uint(f);
  x += 0x7fffu + ((x >> 16) & 1u);   // RNE
  return (short)(x >> 16);
}

__device__ __forceinline__ float fast_exp2(float x) {
#if __has_builtin(__builtin_amdgcn_exp2f)
  return __builtin_amdgcn_exp2f(x);
#else
  return exp2f(x);
#endif
}

// pack two f32 -> one u32 of 2 bf16 (RNE), single v_cvt_pk_bf16_f32
__device__ __forceinline__ unsigned int pack_bf2(float lo, float hi) {
  unsigned int r;
  asm("v_cvt_pk_bf16_f32 %0, %1, %2" : "=v"(r) : "v"(lo), "v"(hi));
  return r;
}

// async global->LDS, 16B/lane. LDS dest = wave-uniform base + lane*16 (linear!).
// Global source is PER-LANE -> swizzled layouts via pre-swizzled source addr (m173).
__device__ __forceinline__ void gl2lds16(const void* g, void* l) {
  __builtin_amdgcn_global_load_lds(
      (const __attribute__((address_space(1))) void*)g,
      (__attribute__((address_space(3))) void*)l, 16, 0, 0);
}

// ---------------- merged prep: fp32->bf16 for X/Wq/Wk/Wv/Wo + RoPE table ----------------
// Region boundaries are multiples of 256 units -> block-uniform branches.
__global__ __launch_bounds__(256) void prep_kernel(
    const float* __restrict__ X,  const float* __restrict__ Wq,
    const float* __restrict__ Wk, const float* __restrict__ Wv,
    const float* __restrict__ Wo,
    short* __restrict__ Xb, short* __restrict__ Wqkv, short* __restrict__ Wob,
    float2* __restrict__ RT)
{
  const int bid = blockIdx.x;
  if (bid < 8192) {
    int u = bid * 256 + threadIdx.x;          // one 4-elem unit per thread
    const float* src; short* dst; int base;
    if (u < 1048576)      { src = X;  dst = Xb;              base = u; }
    else if (u < 1310720) { src = Wq; dst = Wqkv;            base = u - 1048576; }
    else if (u < 1572864) { src = Wk; dst = Wqkv + 1048576;  base = u - 1310720; }
    else if (u < 1835008) { src = Wv; dst = Wqkv + 2097152;  base = u - 1572864; }
    else                  { src = Wo; dst = Wob;             base = u - 1835008; }
    int i = base * 4;
    float4 v = *(const float4*)(src + i);
    short4v o;
    o.x = f2bf(v.x); o.y = f2bf(v.y); o.z = f2bf(v.z); o.w = f2bf(v.w);
    *(short4v*)(dst + i) = o;
  } else {
    int idx = (bid - 8192) * 256 + threadIdx.x;   // 65536 RT entries
    int s = idx >> 5, f = idx & 31;
    float inv = exp2f(-NLOG2TH_64 * (float)(2 * f));
    float ang = (float)s * inv;
    float sn, cs;
    sincosf(ang, &sn, &cs);
    RT[idx] = make_float2(sn, cs);
  }
}

// ---------------- GEMM: C = A(bf16 MxK) * Bw(bf16 NxK)^T ----------------
// K-loop: BK=32, gload_lds staging, DOUBLE-BUFFERED single-barrier protocol
// (the attn kernel's proven scheme): stage next tile into buf^1 before
// computing current; one __syncthreads per K-step (was 2) both drains the
// async loads and fences the buffer swap. LDS: 2 x 16KB inside the 34.8KB
// epilogue union. MODE 1 epilogue: Q gets RoPE + softmax scale; V transposed.
template<int MODE>
__global__ __launch_bounds__(256) void gemm_bt(
    const short* __restrict__ A, const short* __restrict__ Bw,
    float* __restrict__ Cf,
    short* __restrict__ Qout, short* __restrict__ Kout, short* __restrict__ Vout,
    const float2* __restrict__ RT,
    int Ndim, int Kdim)
{
  __shared__ __align__(16) short smem[17408];
  short (*st)[136] = (short(*)[136])smem;
  char* smemb = (char*)smem;

  const int tid  = threadIdx.x;
  const int lane = tid & 63;
  const int wid  = tid >> 6;
  const int wr = wid >> 1, wc = wid & 1;
  const int tile_m = blockIdx.x * 128;
  const int tile_n = blockIdx.y * 128;
  const int lrow = lane & 15;
  const int kgrp = lane >> 4;

  const int r0 = tid >> 2;
  const int sc = (tid & 3) * 8;
  // per-buffer byte offsets (buffer b at byte b*16384):
  const int lA0 = wid * 1024;
  const int lA1 = 4096  + wid * 1024;
  const int lB0 = 8192  + wid * 1024;
  const int lB1 = 12288 + wid * 1024;
  const short* gA0 = A  + (size_t)(tile_m + r0)      * Kdim + sc;
  const short* gA1 = A  + (size_t)(tile_m + r0 + 64) * Kdim + sc;
  const short* gB0 = Bw + (size_t)(tile_n + r0)      * Kdim + sc;
  const short* gB1 = Bw + (size_t)(tile_n + r0 + 64) * Kdim + sc;

  f32x4 acc[4][4];
#pragma unroll
  for (int i = 0; i < 4; i++)
#pragma unroll
    for (int j = 0; j < 4; j++) acc[i][j] = (f32x4)0.0f;

  // prologue: stage k-tile 0 into buffer 0
  gl2lds16(gA0, smemb + lA0);
  gl2lds16(gA1, smemb + lA1);
  gl2lds16(gB0, smemb + lB0);
  gl2lds16(gB1, smemb + lB1);
  __syncthreads();

  int cur = 0;
  for (int k0 = 0; k0 < Kdim; k0 += 32) {
    // stage next tile into the other buffer (async; latency hides under MFMA)
    if (k0 + 32 < Kdim) {
      const int nbo = (cur ^ 1) * 16384;
      gl2lds16(gA0 + k0 + 32, smemb + nbo + lA0);
      gl2lds16(gA1 + k0 + 32, smemb + nbo + lA1);
      gl2lds16(gB0 + k0 + 32, smemb + nbo + lB0);
      gl2lds16(gB1 + k0 + 32, smemb + nbo + lB1);
    }
    // compute current buffer
    const int cb = cur * 8192;   // short offset of this buffer
    bf16x8 af[4], bfr[4];
#pragma unroll
    for (int i = 0; i < 4; i++)
      af[i]  = *(const bf16x8*)&smem[cb + (wr*64 + i*16 + lrow)*32 + kgrp*8];
#pragma unroll
    for (int j = 0; j < 4; j++)
      bfr[j] = *(const bf16x8*)&smem[cb + 4096 + (wc*64 + j*16 + lrow)*32 + kgrp*8];
#pragma unroll
    for (int i = 0; i < 4; i++)
#pragma unroll
      for (int j = 0; j < 4; j++)
        acc[i][j] = __builtin_amdgcn_mfma_f32_16x16x32_bf16(af[i], bfr[j], acc[i][j], 0, 0, 0);
    // single barrier: drains next-tile loads AND fences reads of cur
    __syncthreads();
    cur ^= 1;
  }

  if (MODE == 0) {
#pragma unroll
    for (int i = 0; i < 4; i++)
#pragma unroll
      for (int j = 0; j < 4; j++)
#pragma unroll
        for (int r = 0; r < 4; r++) {
          int mr = tile_m + wr*64 + i*16 + kgrp*4 + r;
          int nc = tile_n + wc*64 + j*16 + lrow;
          Cf[(size_t)mr * Ndim + nc] = acc[i][j][r];
        }
  } else {
    const int sel = tile_n >> 10;
#pragma unroll
    for (int i = 0; i < 4; i++)
#pragma unroll
      for (int j = 0; j < 4; j++)
#pragma unroll
        for (int r = 0; r < 4; r++) {
          float val   = acc[i][j][r];
          float other = __shfl_xor(val, 1, 64);
          int row = wr*64 + i*16 + kgrp*4 + r;
          int col = wc*64 + j*16 + lrow;
          short bv;
          if (sel == 2) {
            bv = f2bf(val);
          } else {
            int c = col & 63;
            int s = (tile_m + row) & 2047;
            float2 t = RT[(s << 5) + (c >> 1)];
            float rot = ((c & 1) == 0) ? (val * t.y - other * t.x)
                                       : (other * t.x + val * t.y);
            if (sel == 0) rot *= LOG2E_DIV8;
            bv = f2bf(rot);
          }
          st[row][col] = bv;
        }
    __syncthreads();
    if (sel < 2) {
      short* Out = (sel == 0) ? Qout : Kout;
#pragma unroll
      for (int p = 0; p < 8; p++) {
        int row = p*16 + (tid >> 4);
        int col = (tid & 15) * 8;
        bf16x8 v = *(const bf16x8*)&st[row][col];
        int mr = tile_m + row; int b = mr >> 11, s = mr & 2047;
        int nc = tile_n + col; int nn = nc & 1023;
        int h = nn >> 6, c = nn & 63;
        *(bf16x8*)&Out[((size_t)((b*Hdim + h)*Sdim + s))*DKdim + c] = v;
      }
    } else {
#pragma unroll
      for (int p = 0; p < 8; p++) {
        int col = p*16 + (tid >> 4);
        int sl  = (tid & 15) * 8;
        bf16x8 v;
#pragma unroll
        for (int e = 0; e < 8; e++) v[e] = st[sl + e][col];
        int nc = tile_n + col; int nn = nc & 1023;
        int h = nn >> 6, c = nn & 63;
        int m0 = tile_m + sl; int b = m0 >> 11, s0 = m0 & 2047;
        *(bf16x8*)&Vout[((size_t)((b*Hdim + h)*DKdim + c))*Sdim + s0] = v;
      }
    }
  }
}

// ---------------- flash attention, causal — KVBLK=128, gload_lds staging ----------------
// (round-17/20, passing) 1 block = 128 q-rows, 4 waves x 32 rows.
// K [128][128B] + V [64][256B] double-buffered; staging via global_load_lds
// with linear dest + pre-swizzled source; swapped QK^T P-path.
__global__ __launch_bounds__(256, 2) void attn_kernel(
    const short* __restrict__ Q, const short* __restrict__ K,
    const short* __restrict__ Vt, short* __restrict__ O)
{
  const int bh = blockIdx.y;
  const int qt = (bh & 16) ? (int)blockIdx.x : (15 - (int)blockIdx.x);
  const int bq0 = qt * 128;
  const int tid  = threadIdx.x;
  const int wave = tid >> 6;
  const int lane = tid & 63;
  const int lrow = lane & 15, kgrp = lane >> 4;
  const short* Qb = Q  + (size_t)bh * Sdim * DKdim;
  const short* Kb = K  + (size_t)bh * Sdim * DKdim;
  const short* Vb = Vt + (size_t)bh * DKdim * Sdim;

  __shared__ __align__(16) char Kl[2][16384];  // [buf][128 kv rows][128 B]
  __shared__ __align__(16) char Vl[2][16384];  // [buf][64 d rows][256 B]
  __shared__ __align__(16) char lPb[16384];    // per-wave P scratch (4KB each)

  const int q0w   = bq0 + wave*32;
  const int NT_w  = (q0w >> 6) + 1;            // this wave's causal 64-tile count
  const int NTP   = qt + 1;                    // block 128-tile count
  const int swz   = (lrow & 7) << 4;
  const int rowbase = wave*4096 + lrow*128;

  const int ldsoff = wave*4096;

  // Q fragments (B-operand), pre-scaled
  bf16x8 qf[2][2];
#pragma unroll
  for (int t = 0; t < 2; t++) {
    qf[t][0] = *(const bf16x8*)&Qb[(q0w + t*16 + lrow) * DKdim + kgrp*8];
    qf[t][1] = *(const bf16x8*)&Qb[(q0w + t*16 + lrow) * DKdim + 32 + kgrp*8];
  }

  f32x4 o[2][4];
  float psum[2] = {0.0f, 0.0f};
#pragma unroll
  for (int t = 0; t < 2; t++)
#pragma unroll
    for (int n = 0; n < 4; n++) o[t][n] = (f32x4)0.0f;

  // ---- prologue: stage 128-tile 0 via global_load_lds ----
#pragma unroll
  for (int q = 0; q < 4; q++) {
    int c = wave*256 + q*64 + lane;
    int krow = c >> 3, kc16 = c & 7;
    gl2lds16((const char*)Kb + (size_t)krow * 128 + ((kc16*16) ^ ((krow & 7) << 4)),
             (char*)Kl[0] + ldsoff + q*1024);
    int vrow = c >> 4, vc16 = c & 15;
    gl2lds16((const char*)Vb + (size_t)vrow * (Sdim*2) + ((vc16*16) ^ ((vrow & 7) << 4)),
             (char*)Vl[0] + ldsoff + q*1024);
  }
  __syncthreads();

  int cur = 0;
  for (int it = 0; it < NTP; ++it) {
    const bool havenext = (it + 1 < NTP);
    // ---- issue next 128-tile gload_lds into the other buffer (async) ----
    if (havenext) {
      const int nkv = (it + 1) << 7;
      char* Kd = (char*)Kl[cur ^ 1] + ldsoff;
      char* Vd = (char*)Vl[cur ^ 1] + ldsoff;
#pragma unroll
      for (int q = 0; q < 4; q++) {
        int c = wave*256 + q*64 + lane;
        int krow = c >> 3, kc16 = c & 7;
        gl2lds16((const char*)Kb + (size_t)(nkv + krow) * 128 + ((kc16*16) ^ ((krow & 7) << 4)),
                 Kd + q*1024);
        int vrow = c >> 4, vc16 = c & 15;
        gl2lds16((const char*)Vb + (size_t)vrow * (Sdim*2) + nkv*2 + ((vc16*16) ^ ((vrow & 7) << 4)),
                 Vd + q*1024);
      }
    }
    // ---- two 64-wide sub-tiles over the staged 128-tile ----
#pragma unroll
    for (int stt = 0; stt < 2; ++stt) {
      const int j = 2*it + stt;            // global 64-tile index
      if (j < NT_w) {
        const int kv0 = j << 6;
        const char* Kc = Kl[cur] + stt*8192;
        const char* Vc = Vl[cur];
        const int vbo = stt*128;
        f32x4 sacc[2][4];
#pragma unroll
        for (int t = 0; t < 2; t++)
#pragma unroll
          for (int nch = 0; nch < 4; nch++) sacc[t][nch] = (f32x4)0.0f;
        __builtin_amdgcn_s_setprio(1);
#pragma unroll
        for (int nch = 0; nch < 4; nch++) {
          int rb = (nch*16 + lrow)*128;
          bf16x8 kf0 = *(const bf16x8*)(Kc + rb + ((kgrp*16) ^ swz));
          bf16x8 kf1 = *(const bf16x8*)(Kc + rb + ((kgrp*16 + 64) ^ swz));
          sacc[0][nch] = __builtin_amdgcn_mfma_f32_16x16x32_bf16(kf0, qf[0][0], sacc[0][nch], 0, 0, 0);
          sacc[0][nch] = __builtin_amdgcn_mfma_f32_16x16x32_bf16(kf1, qf[0][1], sacc[0][nch], 0, 0, 0);
          sacc[1][nch] = __builtin_amdgcn_mfma_f32_16x16x32_bf16(kf0, qf[1][0], sacc[1][nch], 0, 0, 0);
          sacc[1][nch] = __builtin_amdgcn_mfma_f32_16x16x32_bf16(kf1, qf[1][1], sacc[1][nch], 0, 0, 0);
        }
        __builtin_amdgcn_s_setprio(0);
        const bool diag = (j == NT_w - 1);
#pragma unroll
        for (int t = 0; t < 2; t++) {
          const int q_abs = q0w + t*16 + lrow;
#pragma unroll
          for (int nch = 0; nch < 4; nch++) {
            const int kbase = kv0 + nch*16 + kgrp*4;
            float p[4];
#pragma unroll
            for (int r = 0; r < 4; r++) {
              float e = fast_exp2(sacc[t][nch][r]);
              p[r] = (diag && (kbase + r > q_abs)) ? 0.0f : e;
            }
            psum[t] += (p[0] + p[1]) + (p[2] + p[3]);
            uint2v w;
            w.x = pack_bf2(p[0], p[1]);
            w.y = pack_bf2(p[2], p[3]);
            *(uint2v*)(lPb + rowbase + t*2048 + ((nch*32 + kgrp*8) ^ swz)) = w;
          }
        }
        asm volatile("s_waitcnt lgkmcnt(0)" ::: "memory");
        __builtin_amdgcn_sched_barrier(0);
        bf16x8 pa[2][2];
#pragma unroll
        for (int t = 0; t < 2; t++)
#pragma unroll
          for (int h = 0; h < 2; h++)
            pa[t][h] = *(const bf16x8*)(lPb + rowbase + t*2048 + ((h*64 + kgrp*16) ^ swz));
        __builtin_amdgcn_s_setprio(1);
#pragma unroll
        for (int n = 0; n < 4; n++) {
          int rb = (n*16 + lrow)*256 + vbo;
          bf16x8 vf0 = *(const bf16x8*)(Vc + rb + ((kgrp*16) ^ swz));
          bf16x8 vf1 = *(const bf16x8*)(Vc + rb + ((kgrp*16 + 64) ^ swz));
          o[0][n] = __builtin_amdgcn_mfma_f32_16x16x32_bf16(pa[0][0], vf0, o[0][n], 0, 0, 0);
          o[0][n] = __builtin_amdgcn_mfma_f32_16x16x32_bf16(pa[0][1], vf1, o[0][n], 0, 0, 0);
          o[1][n] = __builtin_amdgcn_mfma_f32_16x16x32_bf16(pa[1][0], vf0, o[1][n], 0, 0, 0);
          o[1][n] = __builtin_amdgcn_mfma_f32_16x16x32_bf16(pa[1][1], vf1, o[1][n], 0, 0, 0);
        }
        __builtin_amdgcn_s_setprio(0);
      }
    }
    // barrier: drains vmcnt(0) -> next buffer staged; also fences buffer swap
    __syncthreads();
    cur ^= 1;
  }

  // ---- epilogue: row-sums wave-local; redistribute via shuffles ----
  float vt[2];
#pragma unroll
  for (int t = 0; t < 2; t++) {
    float v = psum[t];
    v += __shfl_xor(v, 16, 64);
    v += __shfl_xor(v, 32, 64);
    vt[t] = v;
  }
  const int hh = bh & 15, b = bh >> 4;
#pragma unroll
  for (int t = 0; t < 2; t++)
#pragma unroll
    for (int r = 0; r < 4; r++) {
      float rs = __frcp_rn(__shfl(vt[t], kgrp*4 + r, 64));
      int row = q0w + t*16 + kgrp*4 + r;
#pragma unroll
      for (int n = 0; n < 4; n++) {
        int col = hh*64 + n*16 + lrow;
        O[(size_t)(b*Sdim + row) * Ddim + col] = f2bf(o[t][n][r] * rs);
      }
    }
}

// ---------------- launch ----------------
extern "C" void kernel_launch(void* const* d_in, const int* in_sizes, int n_in,
                              void* d_out, int out_size, void* d_ws, size_t ws_size,
                              hipStream_t stream) {
  const float* X  = (const float*)d_in[0];
  const float* Wq = (const float*)d_in[1];
  const float* Wk = (const float*)d_in[2];
  const float* Wv = (const float*)d_in[3];
  const float* Wo = (const float*)d_in[4];
  float* out = (float*)d_out;
  char* ws = (char*)d_ws;

  short* Xb   = (short*)(ws);                    //  8 MB  [4096][1024]
  short* Wqkv = (short*)(ws + 8388608);          //  6 MB  [3072][1024]
  short* Wob  = (short*)(ws + 14680064);         //  2 MB  [1024][1024]
  short* Qr   = (short*)(ws + 16777216);         //  8 MB  [BH][S][64]
  short* Kr   = (short*)(ws + 25165824);         //  8 MB  [BH][S][64]
  short* Vt   = (short*)(ws + 33554432);         //  8 MB  [BH][64][S]
  short* Ob   = (short*)(ws + 41943040);         //  8 MB  [4096][1024]
  float2* RT  = (float2*)(ws + 41943040);        // 512 KB, aliases Ob (consumed first)

  prep_kernel<<<8448, 256, 0, stream>>>(X, Wq, Wk, Wv, Wo, Xb, Wqkv, Wob, RT);

  gemm_bt<1><<<dim3(32, 24), 256, 0, stream>>>(Xb, Wqkv, (float*)nullptr,
                                               Qr, Kr, Vt, RT, 3072, 1024);
  attn_kernel<<<dim3(16, 32), 256, 0, stream>>>(Qr, Kr, Vt, Ob);
  gemm_bt<0><<<dim3(32, 8), 256, 0, stream>>>(Ob, Wob, out,
                                              nullptr, nullptr, nullptr, RT, 1024, 1024);
}